// Round 11
// baseline (145.324 us; speedup 1.0000x reference)
//
#include <hip/hip_runtime.h>
#include <cstddef>

#define NN 256
#define DD 1024
#define CC 4
#define NCOL 16            // columns per block (64B line = 16 floats)
#define NB 64              // NB * NCOL = DD
#define NT 512             // 4 col-quads x 128 row-groups
#define ROOT (NN - 1)

struct St {
  float4 p[8];   // 8 rows of P[dep][r][c4*4..+3]
  float4 x[2];   // 8 rows of emb[node] (loaded only on last-child stages)
};

__device__ __forceinline__ float4 relu4(float4 v) {
  float4 r;
  r.x = fmaxf(v.x, 0.f); r.y = fmaxf(v.y, 0.f);
  r.z = fmaxf(v.z, 0.f); r.w = fmaxf(v.w, 0.f);
  return r;
}

__device__ __forceinline__ float4 mul4(float4 a, float4 b) {
  float4 r; r.x = a.x*b.x; r.y = a.y*b.y; r.z = a.z*b.z; r.w = a.w*b.w; return r;
}

__device__ __forceinline__ float4 max4(float4 a, float4 b) {
  float4 r;
  r.x = fmaxf(a.x, b.x); r.y = fmaxf(a.y, b.y);
  r.z = fmaxf(a.z, b.z); r.w = fmaxf(a.w, b.w);
  return r;
}

__device__ __forceinline__ void fma4(float4& acc, float4 m, float s) {
  acc.x = fmaf(m.x, s, acc.x); acc.y = fmaf(m.y, s, acc.y);
  acc.z = fmaf(m.z, s, acc.z); acc.w = fmaf(m.w, s, acc.w);
}

__device__ __forceinline__ void ld_stage(St& S, int e, const float* __restrict__ par,
                                         const float* __restrict__ emb,
                                         const short* e_meta, const short* e_node,
                                         int j0, int c4, int r0) {
  const int meta = e_meta[e];
  const int dep = meta & 0x3FFF;
  const float* pb = par + (((size_t)dep) << 20) + (((size_t)r0) << 10) + j0 + (c4 << 2);
#pragma unroll
  for (int q = 0; q < 8; ++q) S.p[q] = *(const float4*)(pb + ((size_t)q << 10));
  if (meta & 0x8000) {  // last child of its node -> x consumed in compute
    const float* xb = emb + (((size_t)e_node[e]) << 10) + r0;
    S.x[0] = *(const float4*)(xb);
    S.x[1] = *(const float4*)(xb + 4);
  }
}

__device__ __forceinline__ void cmp_stage(const St& S, int e, float4* m,
                                          float (*z_loc)[NCOL], float (*s_part)[NCOL],
                                          const short* e_child, const short* e_meta,
                                          const short* e_node, float* __restrict__ out_unused,
                                          int tid, int c4, int wv) {
  const int meta = e_meta[e];
  const int child = e_child[e];
  const float4 u = relu4(*(const float4*)&z_loc[child][c4 << 2]);
  if (meta & 0x4000) {  // first child: init m
#pragma unroll
    for (int q = 0; q < 8; ++q) m[q] = mul4(S.p[q], u);
  } else {
#pragma unroll
    for (int q = 0; q < 8; ++q) m[q] = max4(m[q], mul4(S.p[q], u));
  }
  if (meta & 0x8000) {  // last child: finish node
    float4 acc = {0.f, 0.f, 0.f, 0.f};
    fma4(acc, m[0], S.x[0].x); fma4(acc, m[1], S.x[0].y);
    fma4(acc, m[2], S.x[0].z); fma4(acc, m[3], S.x[0].w);
    fma4(acc, m[4], S.x[1].x); fma4(acc, m[5], S.x[1].y);
    fma4(acc, m[6], S.x[1].z); fma4(acc, m[7], S.x[1].w);
    // reduce over the 16 row-groups within the wave (fixed order -> deterministic)
#pragma unroll
    for (int off = 4; off < 64; off <<= 1) {
      acc.x += __shfl_xor(acc.x, off, 64);
      acc.y += __shfl_xor(acc.y, off, 64);
      acc.z += __shfl_xor(acc.z, off, 64);
      acc.w += __shfl_xor(acc.w, off, 64);
    }
    if ((tid & 63) < 4) *(float4*)&s_part[wv][c4 << 2] = acc;
    __syncthreads();
    const int node = e_node[e];
    if (tid < NCOL) {
      float s = 0.f;
#pragma unroll
      for (int k = 0; k < 8; ++k) s += s_part[k][tid];
      z_loc[node][tid] = s;
    }
    __syncthreads();
  }
}

__global__ __launch_bounds__(NT, 1) void dep_col_kernel(
    const float* __restrict__ emb, const float* __restrict__ par,
    const int* __restrict__ cidx, const int* __restrict__ cdep,
    const unsigned char* __restrict__ cmask, float* __restrict__ out) {
  __shared__ float z_loc[NN][NCOL];       // 16 KB: z for this block's 16 columns
  __shared__ short s_ci[NN][CC];
  __shared__ short s_cd[NN][CC];
  __shared__ short s_nc[NN];
  __shared__ int s_pfx[NN];
  __shared__ unsigned char s_reach[NN];
  __shared__ short s_e_child[NN * CC];    // child-stream (topo order)
  __shared__ short s_e_meta[NN * CC];     // dep | first<<14 | last<<15
  __shared__ short s_e_node[NN * CC];
  __shared__ int s_NE;
  __shared__ int s_flag;
  __shared__ float s_part[8][NCOL];

  const int tid = threadIdx.x;
  const int j0 = blockIdx.x * NCOL;
  const int c4 = tid & 3;        // column quad within the 16-col strip
  const int r0 = (tid >> 2) << 3;  // 8 rows per thread
  const int wv = tid >> 6;       // wave id 0..7

  // ---- Phase 1: schedule build (LDS only, identical in every block) ----
  if (tid == 0)
    s_flag = (cmask[1021] == 1 && cmask[1022] == 1 && cmask[1023] == 1);
  __syncthreads();
  const bool m_u8 = (s_flag != 0);
  const int* m32 = (const int*)cmask;
  if (tid < NN) {
    int nc = 0;
#pragma unroll
    for (int c = 0; c < CC; ++c) {
      bool mk = m_u8 ? (cmask[tid * CC + c] != 0) : (m32[tid * CC + c] != 0);
      if (mk) {
        s_ci[tid][nc] = (short)cidx[tid * CC + c];
        s_cd[tid][nc] = (short)cdep[tid * CC + c];
        ++nc;
      }
    }
    s_nc[tid] = (short)nc;
    s_reach[tid] = (tid == ROOT) ? 1 : 0;
  }
  __syncthreads();

  // Reachability fixpoint (root downward; <= depth passes)
  for (int it = 0; it < NN + 2; ++it) {
    if (tid == 0) s_flag = 0;
    __syncthreads();
    if (tid < NN && s_reach[tid] && s_nc[tid] > 0) {
      for (int c = 0; c < s_nc[tid]; ++c) {
        const int ch = s_ci[tid][c];
        if (!s_reach[ch]) { s_reach[ch] = 1; s_flag = 1; }
      }
    }
    __syncthreads();
    const int chg = s_flag;
    __syncthreads();
    if (!chg) break;
  }

  // Prefix-sum of per-node child counts (reachable internal only)
  const int wgt = (tid < NN && s_reach[tid] && s_nc[tid] > 0) ? (int)s_nc[tid] : 0;
  if (tid < NN) s_pfx[tid] = wgt;
  __syncthreads();
  for (int off = 1; off < NN; off <<= 1) {
    int v = 0;
    if (tid < NN && tid >= off) v = s_pfx[tid - off];
    __syncthreads();
    if (tid < NN) s_pfx[tid] += v;
    __syncthreads();
  }
  // Emit child-stream entries (ascending node index = topological order)
  if (tid < NN && wgt > 0) {
    const int st = s_pfx[tid] - wgt;
    for (int c = 0; c < wgt; ++c) {
      s_e_child[st + c] = s_ci[tid][c];
      int meta = (int)s_cd[tid][c];
      if (c == 0) meta |= 1 << 14;
      if (c == wgt - 1) meta |= 1 << 15;
      s_e_meta[st + c] = (short)meta;
      s_e_node[st + c] = (short)tid;
    }
  }
  if (tid == NN - 1) s_NE = s_pfx[NN - 1];

  // Init z_loc for all nodes from embeddings (leaf z = x; internal overwritten)
#pragma unroll
  for (int q = 0; q < 2; ++q) {
    const int v = tid + q * NT;      // float4 id 0..1023
    const int n = v >> 2;
    const int cq = v & 3;
    const float4 e = *(const float4*)(emb + (((size_t)n) << 10) + j0 + (cq << 2));
    *(float4*)&z_loc[n][cq << 2] = e;
  }
  __syncthreads();
  const int NE = s_NE;

  // ---- Phase 2: child-granular 2-stage pipelined serial walk ----
  St A, B;
  float4 m[8];
  if (NE > 0) ld_stage(A, 0, par, emb, s_e_meta, s_e_node, j0, c4, r0);
  int e = 0;
  while (e < NE) {
    if (e + 1 < NE) ld_stage(B, e + 1, par, emb, s_e_meta, s_e_node, j0, c4, r0);
    cmp_stage(A, e, m, z_loc, s_part, s_e_child, s_e_meta, s_e_node, out, tid, c4, wv);
    if (++e >= NE) break;
    if (e + 1 < NE) ld_stage(A, e + 1, par, emb, s_e_meta, s_e_node, j0, c4, r0);
    cmp_stage(B, e, m, z_loc, s_part, s_e_child, s_e_meta, s_e_node, out, tid, c4, wv);
    ++e;
  }

  // ---- Output: root z for this block's 16 columns ----
  if (tid < NCOL) out[j0 + tid] = z_loc[ROOT][tid];
}

extern "C" void kernel_launch(void* const* d_in, const int* in_sizes, int n_in,
                              void* d_out, int out_size, void* d_ws, size_t ws_size,
                              hipStream_t stream) {
  const float* emb = (const float*)d_in[0];
  const float* par = (const float*)d_in[1];
  const int* cidx = (const int*)d_in[2];
  const int* cdep = (const int*)d_in[3];
  const unsigned char* cmask = (const unsigned char*)d_in[4];
  float* out = (float*)d_out;

  hipLaunchKernelGGL(dep_col_kernel, dim3(NB), dim3(NT), 0, stream, emb, par,
                     cidx, cdep, cmask, out);
}

// Round 12
// 124.671 us; speedup vs baseline: 1.1657x; 1.1657x over previous
//
#include <hip/hip_runtime.h>
#include <cstddef>

#define NN 256
#define DD 1024
#define CC 4
#define NT 512             // threads: each owns 2 rows x 4 cols
#define ROOT (NN - 1)

// Block mapping: s = bid & 63 (16-col strip), q = bid >> 6 (4-col quad).
// bid = q*64 + s  =>  bid % 8 == s % 8: all 4 quads of a strip share an XCD,
// so the XCD L2 dedups the 4x line overfetch of row-major 16B reads.

struct St {
  float4 p0, p1;  // P[dep][r2][j0..3], P[dep][r2+1][j0..3]
  float x0, x1;   // emb[node][r2], emb[node][r2+1] (last-child stages only)
};

__device__ __forceinline__ float4 relu4(float4 v) {
  float4 r;
  r.x = fmaxf(v.x, 0.f); r.y = fmaxf(v.y, 0.f);
  r.z = fmaxf(v.z, 0.f); r.w = fmaxf(v.w, 0.f);
  return r;
}
__device__ __forceinline__ float4 mul4(float4 a, float4 b) {
  float4 r; r.x = a.x*b.x; r.y = a.y*b.y; r.z = a.z*b.z; r.w = a.w*b.w; return r;
}
__device__ __forceinline__ float4 max4(float4 a, float4 b) {
  float4 r;
  r.x = fmaxf(a.x, b.x); r.y = fmaxf(a.y, b.y);
  r.z = fmaxf(a.z, b.z); r.w = fmaxf(a.w, b.w);
  return r;
}
__device__ __forceinline__ void fma4(float4& acc, float4 m, float s) {
  acc.x = fmaf(m.x, s, acc.x); acc.y = fmaf(m.y, s, acc.y);
  acc.z = fmaf(m.z, s, acc.z); acc.w = fmaf(m.w, s, acc.w);
}

__device__ __forceinline__ void ld_stage(St& S, int e, const float* __restrict__ par,
                                         const float* __restrict__ emb,
                                         const short* e_meta, const short* e_node,
                                         int j0, int r2) {
  const int meta = e_meta[e];
  const int dep = meta & 0x3FFF;
  const float* pb = par + (((size_t)dep) << 20) + (((size_t)r2) << 10) + j0;
  S.p0 = *(const float4*)(pb);
  S.p1 = *(const float4*)(pb + DD);
  if (meta & 0x8000) {
    const float2 xx = *(const float2*)(emb + (((size_t)e_node[e]) << 10) + r2);
    S.x0 = xx.x; S.x1 = xx.y;
  }
}

__device__ __forceinline__ void cmp_stage(const St& S, int e, float4& m0, float4& m1,
                                          float (*z_loc)[4], float (*s_part)[4],
                                          const short* e_child, const short* e_meta,
                                          const short* e_node, int tid) {
  const int meta = e_meta[e];
  const float4 u = relu4(*(const float4*)z_loc[e_child[e]]);  // LDS broadcast
  if (meta & 0x4000) {  // first child of node
    m0 = mul4(S.p0, u);
    m1 = mul4(S.p1, u);
  } else {
    m0 = max4(m0, mul4(S.p0, u));
    m1 = max4(m1, mul4(S.p1, u));
  }
  if (meta & 0x8000) {  // last child: finish node
    float4 acc = {0.f, 0.f, 0.f, 0.f};
    fma4(acc, m0, S.x0);
    fma4(acc, m1, S.x1);
    // 64-lane butterfly (fixed order -> deterministic)
#pragma unroll
    for (int off = 1; off < 64; off <<= 1) {
      acc.x += __shfl_xor(acc.x, off, 64);
      acc.y += __shfl_xor(acc.y, off, 64);
      acc.z += __shfl_xor(acc.z, off, 64);
      acc.w += __shfl_xor(acc.w, off, 64);
    }
    if ((tid & 63) == 0) *(float4*)s_part[tid >> 6] = acc;
    __syncthreads();
    if (tid < 4) {
      float s = 0.f;
#pragma unroll
      for (int k = 0; k < 8; ++k) s += s_part[k][tid];
      z_loc[e_node[e]][tid] = s;
    }
    __syncthreads();
  }
}

__global__ __launch_bounds__(NT, 1) void dep_col_kernel(
    const float* __restrict__ emb, const float* __restrict__ par,
    const int* __restrict__ cidx, const int* __restrict__ cdep,
    const unsigned char* __restrict__ cmask, float* __restrict__ out) {
  __shared__ float z_loc[NN][4];       // z for this block's 4 columns
  __shared__ short s_ci[NN][CC];
  __shared__ short s_cd[NN][CC];
  __shared__ short s_nc[NN];
  __shared__ int s_pfx[NN];
  __shared__ unsigned char s_reach[NN];
  __shared__ short s_e_child[NN * CC];  // child-stream (topo order)
  __shared__ short s_e_meta[NN * CC];   // dep | first<<14 | last<<15
  __shared__ short s_e_node[NN * CC];
  __shared__ int s_NE;
  __shared__ int s_flag;
  __shared__ float s_part[8][4];

  const int tid = threadIdx.x;
  const int strip = blockIdx.x & 63;
  const int quad = blockIdx.x >> 6;
  const int j0 = strip * 16 + quad * 4;
  const int r2 = tid << 1;  // 2 rows per thread

  // ---- Phase 1: schedule build (LDS only, identical in every block) ----
  if (tid == 0)
    s_flag = (cmask[1021] == 1 && cmask[1022] == 1 && cmask[1023] == 1);
  __syncthreads();
  const bool m_u8 = (s_flag != 0);
  const int* m32 = (const int*)cmask;
  if (tid < NN) {
    int nc = 0;
#pragma unroll
    for (int c = 0; c < CC; ++c) {
      bool mk = m_u8 ? (cmask[tid * CC + c] != 0) : (m32[tid * CC + c] != 0);
      if (mk) {
        s_ci[tid][nc] = (short)cidx[tid * CC + c];
        s_cd[tid][nc] = (short)cdep[tid * CC + c];
        ++nc;
      }
    }
    s_nc[tid] = (short)nc;
    s_reach[tid] = (tid == ROOT) ? 1 : 0;
  }
  __syncthreads();

  // Reachability fixpoint (root downward; <= depth passes)
  for (int it = 0; it < NN + 2; ++it) {
    if (tid == 0) s_flag = 0;
    __syncthreads();
    if (tid < NN && s_reach[tid] && s_nc[tid] > 0) {
      for (int c = 0; c < s_nc[tid]; ++c) {
        const int ch = s_ci[tid][c];
        if (!s_reach[ch]) { s_reach[ch] = 1; s_flag = 1; }
      }
    }
    __syncthreads();
    const int chg = s_flag;
    __syncthreads();
    if (!chg) break;
  }

  // Prefix-sum of per-node child counts (reachable internal only)
  const int wgt = (tid < NN && s_reach[tid] && s_nc[tid] > 0) ? (int)s_nc[tid] : 0;
  if (tid < NN) s_pfx[tid] = wgt;
  __syncthreads();
  for (int off = 1; off < NN; off <<= 1) {
    int v = 0;
    if (tid < NN && tid >= off) v = s_pfx[tid - off];
    __syncthreads();
    if (tid < NN) s_pfx[tid] += v;
    __syncthreads();
  }
  // Emit child-stream entries (ascending node index = topological order)
  if (tid < NN && wgt > 0) {
    const int st = s_pfx[tid] - wgt;
    for (int c = 0; c < wgt; ++c) {
      s_e_child[st + c] = s_ci[tid][c];
      int meta = (int)s_cd[tid][c];
      if (c == 0) meta |= 1 << 14;
      if (c == wgt - 1) meta |= 1 << 15;
      s_e_meta[st + c] = (short)meta;
      s_e_node[st + c] = (short)tid;
    }
  }
  if (tid == NN - 1) s_NE = s_pfx[NN - 1];

  // Init z_loc from embeddings (leaf z = x; internal overwritten in topo order)
  if (tid < NN) {
    const float4 e = *(const float4*)(emb + (((size_t)tid) << 10) + j0);
    *(float4*)z_loc[tid] = e;
  }
  __syncthreads();
  const int NE = s_NE;

  // ---- Phase 2: 4-deep pipelined serial walk (static stage names) ----
  St A, B, C, D;
  float4 m0, m1;
  if (NE > 0) ld_stage(A, 0, par, emb, s_e_meta, s_e_node, j0, r2);
  if (NE > 1) ld_stage(B, 1, par, emb, s_e_meta, s_e_node, j0, r2);
  if (NE > 2) ld_stage(C, 2, par, emb, s_e_meta, s_e_node, j0, r2);
  int e = 0;
  while (e < NE) {
    if (e + 3 < NE) ld_stage(D, e + 3, par, emb, s_e_meta, s_e_node, j0, r2);
    cmp_stage(A, e, m0, m1, z_loc, s_part, s_e_child, s_e_meta, s_e_node, tid);
    if (++e >= NE) break;
    if (e + 3 < NE) ld_stage(A, e + 3, par, emb, s_e_meta, s_e_node, j0, r2);
    cmp_stage(B, e, m0, m1, z_loc, s_part, s_e_child, s_e_meta, s_e_node, tid);
    if (++e >= NE) break;
    if (e + 3 < NE) ld_stage(B, e + 3, par, emb, s_e_meta, s_e_node, j0, r2);
    cmp_stage(C, e, m0, m1, z_loc, s_part, s_e_child, s_e_meta, s_e_node, tid);
    if (++e >= NE) break;
    if (e + 3 < NE) ld_stage(C, e + 3, par, emb, s_e_meta, s_e_node, j0, r2);
    cmp_stage(D, e, m0, m1, z_loc, s_part, s_e_child, s_e_meta, s_e_node, tid);
    ++e;
  }

  // ---- Output: root z for this block's 4 columns ----
  if (tid < 4) out[j0 + tid] = z_loc[ROOT][tid];
}

extern "C" void kernel_launch(void* const* d_in, const int* in_sizes, int n_in,
                              void* d_out, int out_size, void* d_ws, size_t ws_size,
                              hipStream_t stream) {
  const float* emb = (const float*)d_in[0];
  const float* par = (const float*)d_in[1];
  const int* cidx = (const int*)d_in[2];
  const int* cdep = (const int*)d_in[3];
  const unsigned char* cmask = (const unsigned char*)d_in[4];
  float* out = (float*)d_out;

  hipLaunchKernelGGL(dep_col_kernel, dim3(256), dim3(NT), 0, stream, emb, par,
                     cidx, cdep, cmask, out);
}